// Round 1
// baseline (930.736 us; speedup 1.0000x reference)
//
#include <hip/hip_runtime.h>
#include <hip/hip_bf16.h>

#define B 6
#define S 1024
#define H 12
#define DK 64
#define DM 768
#define M (B*S)      // 6144
#define BH (B*H)     // 72

typedef __bf16 bf16;
typedef __attribute__((ext_vector_type(8))) __bf16 bf16x8;
typedef __attribute__((ext_vector_type(4))) float f32x4;

// ---------------- weight transpose + bf16 convert: wt[z][n][k] = W_z[k][n]
__global__ void k_wt(const float* __restrict__ Wq, const float* __restrict__ Wk,
                     const float* __restrict__ Wv, const float* __restrict__ Wo,
                     bf16* __restrict__ wt) {
  int z = blockIdx.y;
  const float* W = z==0?Wq : z==1?Wk : z==2?Wv : Wo;
  int idx = blockIdx.x*256 + threadIdx.x;   // 0..768*768-1
  int k = idx / DM, n = idx % DM;
  wt[(size_t)z*DM*DM + (size_t)n*DM + k] = (bf16)W[idx];
}

// ---------------- QKV projection: q,k -> [bh][s][dk] bf16 ; v -> [bh][dk][s] bf16
__global__ void k_proj(const float* __restrict__ Q, const float* __restrict__ K,
                       const float* __restrict__ V,
                       const bf16* __restrict__ wt,
                       const float* __restrict__ bq, const float* __restrict__ bk,
                       const float* __restrict__ bv,
                       bf16* __restrict__ qb, bf16* __restrict__ kb, bf16* __restrict__ vt) {
  int z = blockIdx.z;
  const float* X    = z==0?Q : z==1?K : V;
  const float* bias = z==0?bq : z==1?bk : bv;
  const bf16* Wt = wt + (size_t)z*DM*DM;
  int lane = threadIdx.x & 63, wave = threadIdx.x >> 6;
  int m0 = blockIdx.x*64 + wave*16;
  int n0 = blockIdx.y*16;
  int lr = lane & 15, lg = lane >> 4;
  const float* arow = X  + (size_t)(m0+lr)*DM + lg*8;
  const bf16*  brow = Wt + (size_t)(n0+lr)*DM + lg*8;
  f32x4 acc = {0.f,0.f,0.f,0.f};
  for (int k0 = 0; k0 < DM; k0 += 32) {
    bf16x8 a, b;
    #pragma unroll
    for (int j = 0; j < 8; ++j) a[j] = (bf16)arow[k0 + j];
    b = *(const bf16x8*)(brow + k0);
    acc = __builtin_amdgcn_mfma_f32_16x16x32_bf16(a, b, acc, 0, 0, 0);
  }
  int bn = n0 + lr;
  float bs = bias[bn];
  int h = bn >> 6, d = bn & 63;
  #pragma unroll
  for (int r = 0; r < 4; ++r) {
    int m = m0 + lg*4 + r;
    int bb = m >> 10, s = m & 1023;
    float val = acc[r] + bs;
    if (z == 0)      qb[((size_t)(bb*H + h)*S + s)*DK + d] = (bf16)val;
    else if (z == 1) kb[((size_t)(bb*H + h)*S + s)*DK + d] = (bf16)val;
    else             vt[((size_t)(bb*H + h)*DK + d)*S + s] = (bf16)val;
  }
}

// ---------------- scores = (q k^T)/8, masked -> attn region of d_out (pre-softmax)
__global__ void k_scores(const bf16* __restrict__ qb, const bf16* __restrict__ kb,
                         const unsigned char* __restrict__ mask,
                         float* __restrict__ attn) {
  int bh = blockIdx.z; int b = bh / H;
  int lane = threadIdx.x & 63, wave = threadIdx.x >> 6;
  int s0  = blockIdx.x*64 + wave*16;
  int sp0 = blockIdx.y*16;
  int lr = lane & 15, lg = lane >> 4;
  const bf16* qrow = qb + ((size_t)bh*S + s0  + lr)*DK + lg*8;
  const bf16* krow = kb + ((size_t)bh*S + sp0 + lr)*DK + lg*8;
  f32x4 acc = {0.f,0.f,0.f,0.f};
  bf16x8 a0 = *(const bf16x8*)qrow;
  bf16x8 b0 = *(const bf16x8*)krow;
  bf16x8 a1 = *(const bf16x8*)(qrow + 32);
  bf16x8 b1 = *(const bf16x8*)(krow + 32);
  acc = __builtin_amdgcn_mfma_f32_16x16x32_bf16(a0, b0, acc, 0, 0, 0);
  acc = __builtin_amdgcn_mfma_f32_16x16x32_bf16(a1, b1, acc, 0, 0, 0);
  int sc = sp0 + lr;
  #pragma unroll
  for (int r = 0; r < 4; ++r) {
    int sr = s0 + lg*4 + r;
    float v = mask[((size_t)b*S + sr)*S + sc] ? -1e9f : acc[r]*0.125f;
    attn[((size_t)bh*S + sr)*S + sc] = v;
  }
}

// ---------------- in-place row softmax over 1024
__global__ void k_softmax(float* __restrict__ attn) {
  size_t row = blockIdx.x;
  float* p = attn + row*S;
  int tid = threadIdx.x;
  float4 v = ((float4*)p)[tid];
  float mx = fmaxf(fmaxf(v.x,v.y),fmaxf(v.z,v.w));
  #pragma unroll
  for (int off=32; off; off>>=1) mx = fmaxf(mx, __shfl_xor(mx,off));
  __shared__ float sm[4];
  int w = tid>>6;
  if ((tid&63)==0) sm[w]=mx;
  __syncthreads();
  mx = fmaxf(fmaxf(sm[0],sm[1]),fmaxf(sm[2],sm[3]));
  float ex=__expf(v.x-mx), ey=__expf(v.y-mx), ez=__expf(v.z-mx), ew=__expf(v.w-mx);
  float sum = ex+ey+ez+ew;
  #pragma unroll
  for (int off=32; off; off>>=1) sum += __shfl_xor(sum,off);
  __syncthreads();
  if ((tid&63)==0) sm[w]=sum;
  __syncthreads();
  float inv = 1.f/(sm[0]+sm[1]+sm[2]+sm[3]);
  float4 o; o.x=ex*inv; o.y=ey*inv; o.z=ez*inv; o.w=ew*inv;
  ((float4*)p)[tid]=o;
}

// ---------------- context = attn @ v -> ctx[b][s][h*64+d] bf16
__global__ void k_ctx(const float* __restrict__ attn, const bf16* __restrict__ vt,
                      bf16* __restrict__ ctx) {
  int bh = blockIdx.z; int b = bh/H, h = bh - b*H;
  int lane = threadIdx.x & 63, wave = threadIdx.x >> 6;
  int s0 = blockIdx.x*64 + wave*16;
  int lr = lane&15, lg = lane>>4;
  const float* arow = attn + ((size_t)bh*S + s0 + lr)*S + lg*8;
  const bf16* vb0 = vt + (size_t)bh*DK*S;   // [64][1024]
  f32x4 acc[4];
  #pragma unroll
  for (int t=0;t<4;++t) acc[t] = (f32x4){0.f,0.f,0.f,0.f};
  for (int k0 = 0; k0 < S; k0 += 32) {
    bf16x8 a;
    #pragma unroll
    for (int j=0;j<8;++j) a[j] = (bf16)arow[k0+j];
    #pragma unroll
    for (int t=0;t<4;++t) {
      bf16x8 bf = *(const bf16x8*)(vb0 + (size_t)(t*16 + lr)*S + k0 + lg*8);
      acc[t] = __builtin_amdgcn_mfma_f32_16x16x32_bf16(a, bf, acc[t], 0, 0, 0);
    }
  }
  #pragma unroll
  for (int t=0;t<4;++t)
    #pragma unroll
    for (int r=0;r<4;++r) {
      int sr = s0 + lg*4 + r; int d = t*16 + lr;
      ctx[((size_t)b*S + sr)*DM + h*DK + d] = (bf16)acc[t][r];
    }
}

// ---------------- out projection + bias + residual -> x (f32)
__global__ void k_oproj(const bf16* __restrict__ ctx, const bf16* __restrict__ wto,
                        const float* __restrict__ bo, const float* __restrict__ res,
                        float* __restrict__ x) {
  int lane=threadIdx.x&63, wave=threadIdx.x>>6;
  int m0 = blockIdx.x*64 + wave*16, n0 = blockIdx.y*16;
  int lr=lane&15, lg=lane>>4;
  const bf16* arow = ctx + (size_t)(m0+lr)*DM + lg*8;
  const bf16* brow = wto + (size_t)(n0+lr)*DM + lg*8;
  f32x4 acc={0.f,0.f,0.f,0.f};
  for (int k0=0;k0<DM;k0+=32) {
    bf16x8 a = *(const bf16x8*)(arow+k0);
    bf16x8 bfr = *(const bf16x8*)(brow+k0);
    acc = __builtin_amdgcn_mfma_f32_16x16x32_bf16(a, bfr, acc, 0, 0, 0);
  }
  int n = n0+lr; float bb = bo[n];
  #pragma unroll
  for (int r=0;r<4;++r){
    int m = m0+lg*4+r;
    x[(size_t)m*DM+n] = acc[r] + bb + res[(size_t)m*DM+n];
  }
}

// ---------------- layernorm rows of 768 -> d_out
__global__ void k_ln(const float* __restrict__ x, const float* __restrict__ gamma,
                     const float* __restrict__ beta, float* __restrict__ out) {
  int row = blockIdx.x; int tid = threadIdx.x;
  const float* xr = x + (size_t)row*DM;
  float v0 = xr[tid], v1 = xr[tid+256], v2 = xr[tid+512];
  float s = v0+v1+v2, ss = v0*v0+v1*v1+v2*v2;
  #pragma unroll
  for (int off=32; off; off>>=1){ s += __shfl_xor(s,off); ss += __shfl_xor(ss,off); }
  __shared__ float sm[8];
  int w = tid>>6;
  if ((tid&63)==0){ sm[w]=s; sm[4+w]=ss; }
  __syncthreads();
  s = sm[0]+sm[1]+sm[2]+sm[3]; ss = sm[4]+sm[5]+sm[6]+sm[7];
  float mean = s * (1.f/DM);
  float var = ss * (1.f/DM) - mean*mean;
  float rstd = rsqrtf(var + 1e-5f);
  out[(size_t)row*DM + tid]     = (v0-mean)*rstd*gamma[tid]     + beta[tid];
  out[(size_t)row*DM + tid+256] = (v1-mean)*rstd*gamma[tid+256] + beta[tid+256];
  out[(size_t)row*DM + tid+512] = (v2-mean)*rstd*gamma[tid+512] + beta[tid+512];
}

extern "C" void kernel_launch(void* const* d_in, const int* in_sizes, int n_in,
                              void* d_out, int out_size, void* d_ws, size_t ws_size,
                              hipStream_t stream) {
  const float* Q  = (const float*)d_in[0];
  const float* K  = (const float*)d_in[1];
  const float* V  = (const float*)d_in[2];
  const unsigned char* mask = (const unsigned char*)d_in[3];
  const float* Wq = (const float*)d_in[4];
  const float* bq = (const float*)d_in[5];
  const float* Wk = (const float*)d_in[6];
  const float* bk = (const float*)d_in[7];
  const float* Wv = (const float*)d_in[8];
  const float* bv = (const float*)d_in[9];
  const float* Wo = (const float*)d_in[10];
  const float* bo = (const float*)d_in[11];
  const float* gamma = (const float*)d_in[12];
  const float* beta  = (const float*)d_in[13];

  char* ws = (char*)d_ws;
  bf16* qb = (bf16*)(ws + 0);            // [72][1024][64]   9,437,184 B
  bf16* kb = (bf16*)(ws + 9437184);      // [72][1024][64]   9,437,184 B
  bf16* vt = (bf16*)(ws + 18874368);     // [72][64][1024]   9,437,184 B
  bf16* wt = (bf16*)(ws + 28311552);     // [4][768][768]    4,718,592 B
  bf16* ctx = qb;                        // alias: qb dead after k_scores
  float* x  = (float*)(ws + 9437184);    // alias: kb+vt dead after k_ctx

  float* out  = (float*)d_out;                   // [6][1024][768]
  float* attn = out + (size_t)B*S*DM;            // [6][12][1024][1024]

  k_wt     <<<dim3(2304,4),   256, 0, stream>>>(Wq,Wk,Wv,Wo,wt);
  k_proj   <<<dim3(96,48,3),  256, 0, stream>>>(Q,K,V,wt,bq,bk,bv,qb,kb,vt);
  k_scores <<<dim3(16,64,BH), 256, 0, stream>>>(qb,kb,mask,attn);
  k_softmax<<<dim3(BH*S),     256, 0, stream>>>(attn);
  k_ctx    <<<dim3(16,1,BH),  256, 0, stream>>>(attn,vt,ctx);
  k_oproj  <<<dim3(96,48),    256, 0, stream>>>(ctx, wt + (size_t)3*DM*DM, bo, Q, x);
  k_ln     <<<dim3(M),        256, 0, stream>>>(x,gamma,beta,out);
}

// Round 2
// 593.549 us; speedup vs baseline: 1.5681x; 1.5681x over previous
//
#include <hip/hip_runtime.h>
#include <hip/hip_bf16.h>

#define B 6
#define S 1024
#define H 12
#define DK 64
#define DM 768
#define M (B*S)      // 6144
#define BH (B*H)     // 72

typedef __bf16 bf16;
typedef __attribute__((ext_vector_type(8))) __bf16 bf16x8;
typedef __attribute__((ext_vector_type(4))) float f32x4;

// ---------------- weight transpose + bf16 convert: wt[z][n][k] = W_z[k][n]
__global__ void k_wt(const float* __restrict__ Wq, const float* __restrict__ Wk,
                     const float* __restrict__ Wv, const float* __restrict__ Wo,
                     bf16* __restrict__ wt) {
  int z = blockIdx.y;
  const float* W = z==0?Wq : z==1?Wk : z==2?Wv : Wo;
  int idx = blockIdx.x*256 + threadIdx.x;   // 0..768*768-1
  int k = idx / DM, n = idx % DM;
  wt[(size_t)z*DM*DM + (size_t)n*DM + k] = (bf16)W[idx];
}

__device__ __forceinline__ bf16x8 cvt8(const float* p) {
  float4 u0 = *(const float4*)p;
  float4 u1 = *(const float4*)(p + 4);
  bf16x8 r;
  r[0]=(bf16)u0.x; r[1]=(bf16)u0.y; r[2]=(bf16)u0.z; r[3]=(bf16)u0.w;
  r[4]=(bf16)u1.x; r[5]=(bf16)u1.y; r[6]=(bf16)u1.z; r[7]=(bf16)u1.w;
  return r;
}

// ---------------- QKV projection: 128x128 tile, 4 waves 2x2, each wave 4x4 frags
__global__ void k_proj(const float* __restrict__ Q, const float* __restrict__ K,
                       const float* __restrict__ V,
                       const bf16* __restrict__ wt,
                       const float* __restrict__ bq, const float* __restrict__ bk,
                       const float* __restrict__ bv,
                       bf16* __restrict__ qb, bf16* __restrict__ kb, bf16* __restrict__ vt) {
  int z = blockIdx.z;
  const float* X    = z==0?Q : z==1?K : V;
  const float* bias = z==0?bq : z==1?bk : bv;
  const bf16* Wt = wt + (size_t)z*DM*DM;
  int tid = threadIdx.x, lane = tid & 63, w = tid >> 6;
  int wr = w >> 1, wc = w & 1;
  int lr = lane & 15, lg = lane >> 4;
  int m0 = blockIdx.x*128 + wr*64;
  int n0 = blockIdx.y*128 + wc*64;
  const float* abase = X  + (size_t)(m0+lr)*DM;
  const bf16*  bbase = Wt + (size_t)(n0+lr)*DM;
  f32x4 acc[4][4];
  #pragma unroll
  for (int i=0;i<4;++i)
    #pragma unroll
    for (int j=0;j<4;++j) acc[i][j] = (f32x4){0.f,0.f,0.f,0.f};
  for (int k0 = 0; k0 < DM; k0 += 32) {
    bf16x8 af[4], bfr[4];
    #pragma unroll
    for (int mi=0;mi<4;++mi) af[mi] = cvt8(abase + (size_t)mi*16*DM + k0 + lg*8);
    #pragma unroll
    for (int ni=0;ni<4;++ni) bfr[ni] = *(const bf16x8*)(bbase + (size_t)ni*16*DM + k0 + lg*8);
    #pragma unroll
    for (int mi=0;mi<4;++mi)
      #pragma unroll
      for (int ni=0;ni<4;++ni)
        acc[mi][ni] = __builtin_amdgcn_mfma_f32_16x16x32_bf16(af[mi], bfr[ni], acc[mi][ni], 0,0,0);
  }
  #pragma unroll
  for (int ni=0;ni<4;++ni) {
    int n = n0 + ni*16 + lr;
    float bs = bias[n];
    int h = n >> 6, d = n & 63;
    #pragma unroll
    for (int mi=0;mi<4;++mi)
      #pragma unroll
      for (int r=0;r<4;++r) {
        int m = m0 + mi*16 + lg*4 + r;
        int bb = m >> 10, s = m & 1023;
        float val = acc[mi][ni][r] + bs;
        if (z == 0)      qb[((size_t)(bb*H + h)*S + s)*DK + d] = (bf16)val;
        else if (z == 1) kb[((size_t)(bb*H + h)*S + s)*DK + d] = (bf16)val;
        else             vt[((size_t)(bb*H + h)*DK + d)*S + s] = (bf16)val;
      }
  }
}

// ---------------- scores = (q k^T)/8, masked -> attn region (pre-softmax, f32)
__global__ void k_scores(const bf16* __restrict__ qb, const bf16* __restrict__ kb,
                         const unsigned char* __restrict__ mask,
                         float* __restrict__ attn) {
  int bh = blockIdx.z; int b = bh / H;
  int tid = threadIdx.x, lane = tid & 63, w = tid >> 6;
  int wr = w >> 1, wc = w & 1;
  int lr = lane & 15, lg = lane >> 4;
  int s0  = blockIdx.x*128 + wr*64;
  int sp0 = blockIdx.y*128 + wc*64;
  const bf16* qbase = qb + ((size_t)bh*S + s0  + lr)*DK;
  const bf16* kbase = kb + ((size_t)bh*S + sp0 + lr)*DK;
  f32x4 acc[4][4];
  #pragma unroll
  for (int i=0;i<4;++i)
    #pragma unroll
    for (int j=0;j<4;++j) acc[i][j] = (f32x4){0.f,0.f,0.f,0.f};
  #pragma unroll
  for (int k0 = 0; k0 < DK; k0 += 32) {
    bf16x8 af[4], bfr[4];
    #pragma unroll
    for (int mi=0;mi<4;++mi) af[mi]  = *(const bf16x8*)(qbase + (size_t)mi*16*DK + k0 + lg*8);
    #pragma unroll
    for (int ni=0;ni<4;++ni) bfr[ni] = *(const bf16x8*)(kbase + (size_t)ni*16*DK + k0 + lg*8);
    #pragma unroll
    for (int mi=0;mi<4;++mi)
      #pragma unroll
      for (int ni=0;ni<4;++ni)
        acc[mi][ni] = __builtin_amdgcn_mfma_f32_16x16x32_bf16(af[mi], bfr[ni], acc[mi][ni], 0,0,0);
  }
  #pragma unroll
  for (int mi=0;mi<4;++mi)
    #pragma unroll
    for (int r=0;r<4;++r) {
      int sr = s0 + mi*16 + lg*4 + r;
      const unsigned char* mrow = mask + ((size_t)b*S + sr)*S;
      float* arow = attn + ((size_t)bh*S + sr)*S;
      #pragma unroll
      for (int ni=0;ni<4;++ni) {
        int sc = sp0 + ni*16 + lr;
        float v = mrow[sc] ? -1e9f : acc[mi][ni][r]*0.125f;
        arow[sc] = v;
      }
    }
}

// ---------------- in-place row softmax over 1024
__global__ void k_softmax(float* __restrict__ attn) {
  size_t row = blockIdx.x;
  float* p = attn + row*S;
  int tid = threadIdx.x;
  float4 v = ((float4*)p)[tid];
  float mx = fmaxf(fmaxf(v.x,v.y),fmaxf(v.z,v.w));
  #pragma unroll
  for (int off=32; off; off>>=1) mx = fmaxf(mx, __shfl_xor(mx,off));
  __shared__ float sm[8];
  int w = tid>>6;
  if ((tid&63)==0) sm[w]=mx;
  __syncthreads();
  mx = fmaxf(fmaxf(sm[0],sm[1]),fmaxf(sm[2],sm[3]));
  float ex=__expf(v.x-mx), ey=__expf(v.y-mx), ez=__expf(v.z-mx), ew=__expf(v.w-mx);
  float sum = ex+ey+ez+ew;
  #pragma unroll
  for (int off=32; off; off>>=1) sum += __shfl_xor(sum,off);
  __syncthreads();
  if ((tid&63)==0) sm[4+w]=sum;
  __syncthreads();
  float inv = 1.f/(sm[4]+sm[5]+sm[6]+sm[7]);
  float4 o; o.x=ex*inv; o.y=ey*inv; o.z=ez*inv; o.w=ew*inv;
  ((float4*)p)[tid]=o;
}

// ---------------- context = attn @ v : 4 waves x 64 rows, 4x4 frags
__global__ void k_ctx(const float* __restrict__ attn, const bf16* __restrict__ vt,
                      bf16* __restrict__ ctx) {
  int bh = blockIdx.z; int b = bh/H, h = bh - b*H;
  int tid = threadIdx.x, lane = tid & 63, w = tid >> 6;
  int lr = lane & 15, lg = lane >> 4;
  int s0 = blockIdx.x*256 + w*64;
  const float* abase = attn + ((size_t)bh*S + s0 + lr)*S;
  const bf16* vb = vt + (size_t)bh*DK*S;
  f32x4 acc[4][4];
  #pragma unroll
  for (int i=0;i<4;++i)
    #pragma unroll
    for (int j=0;j<4;++j) acc[i][j] = (f32x4){0.f,0.f,0.f,0.f};
  for (int k0 = 0; k0 < S; k0 += 32) {
    bf16x8 af[4], bfr[4];
    #pragma unroll
    for (int mi=0;mi<4;++mi) af[mi] = cvt8(abase + (size_t)mi*16*S + k0 + lg*8);
    #pragma unroll
    for (int ni=0;ni<4;++ni) bfr[ni] = *(const bf16x8*)(vb + (size_t)(ni*16 + lr)*S + k0 + lg*8);
    #pragma unroll
    for (int mi=0;mi<4;++mi)
      #pragma unroll
      for (int ni=0;ni<4;++ni)
        acc[mi][ni] = __builtin_amdgcn_mfma_f32_16x16x32_bf16(af[mi], bfr[ni], acc[mi][ni], 0,0,0);
  }
  #pragma unroll
  for (int mi=0;mi<4;++mi)
    #pragma unroll
    for (int r=0;r<4;++r) {
      int sr = s0 + mi*16 + lg*4 + r;
      bf16* crow = ctx + ((size_t)b*S + sr)*DM + h*DK;
      #pragma unroll
      for (int ni=0;ni<4;++ni)
        crow[ni*16 + lr] = (bf16)acc[mi][ni][r];
    }
}

// ---------------- out projection + bias + residual -> x (f32)
__global__ void k_oproj(const bf16* __restrict__ ctx, const bf16* __restrict__ wto,
                        const float* __restrict__ bo, const float* __restrict__ res,
                        float* __restrict__ x) {
  int tid = threadIdx.x, lane = tid & 63, w = tid >> 6;
  int wr = w >> 1, wc = w & 1;
  int lr = lane & 15, lg = lane >> 4;
  int m0 = blockIdx.x*128 + wr*64;
  int n0 = blockIdx.y*128 + wc*64;
  const bf16* abase = ctx + (size_t)(m0+lr)*DM;
  const bf16* bbase = wto + (size_t)(n0+lr)*DM;
  f32x4 acc[4][4];
  #pragma unroll
  for (int i=0;i<4;++i)
    #pragma unroll
    for (int j=0;j<4;++j) acc[i][j] = (f32x4){0.f,0.f,0.f,0.f};
  for (int k0 = 0; k0 < DM; k0 += 32) {
    bf16x8 af[4], bfr[4];
    #pragma unroll
    for (int mi=0;mi<4;++mi) af[mi]  = *(const bf16x8*)(abase + (size_t)mi*16*DM + k0 + lg*8);
    #pragma unroll
    for (int ni=0;ni<4;++ni) bfr[ni] = *(const bf16x8*)(bbase + (size_t)ni*16*DM + k0 + lg*8);
    #pragma unroll
    for (int mi=0;mi<4;++mi)
      #pragma unroll
      for (int ni=0;ni<4;++ni)
        acc[mi][ni] = __builtin_amdgcn_mfma_f32_16x16x32_bf16(af[mi], bfr[ni], acc[mi][ni], 0,0,0);
  }
  #pragma unroll
  for (int ni=0;ni<4;++ni) {
    int n = n0 + ni*16 + lr;
    float bb = bo[n];
    #pragma unroll
    for (int mi=0;mi<4;++mi)
      #pragma unroll
      for (int r=0;r<4;++r) {
        int m = m0 + mi*16 + lg*4 + r;
        x[(size_t)m*DM + n] = acc[mi][ni][r] + bb + res[(size_t)m*DM + n];
      }
  }
}

// ---------------- layernorm rows of 768 -> d_out
__global__ void k_ln(const float* __restrict__ x, const float* __restrict__ gamma,
                     const float* __restrict__ beta, float* __restrict__ out) {
  int row = blockIdx.x; int tid = threadIdx.x;
  const float* xr = x + (size_t)row*DM;
  float v0 = xr[tid], v1 = xr[tid+256], v2 = xr[tid+512];
  float s = v0+v1+v2, ss = v0*v0+v1*v1+v2*v2;
  #pragma unroll
  for (int off=32; off; off>>=1){ s += __shfl_xor(s,off); ss += __shfl_xor(ss,off); }
  __shared__ float sm[8];
  int w = tid>>6;
  if ((tid&63)==0){ sm[w]=s; sm[4+w]=ss; }
  __syncthreads();
  s = sm[0]+sm[1]+sm[2]+sm[3]; ss = sm[4]+sm[5]+sm[6]+sm[7];
  float mean = s * (1.f/DM);
  float var = ss * (1.f/DM) - mean*mean;
  float rstd = rsqrtf(var + 1e-5f);
  out[(size_t)row*DM + tid]     = (v0-mean)*rstd*gamma[tid]     + beta[tid];
  out[(size_t)row*DM + tid+256] = (v1-mean)*rstd*gamma[tid+256] + beta[tid+256];
  out[(size_t)row*DM + tid+512] = (v2-mean)*rstd*gamma[tid+512] + beta[tid+512];
}

extern "C" void kernel_launch(void* const* d_in, const int* in_sizes, int n_in,
                              void* d_out, int out_size, void* d_ws, size_t ws_size,
                              hipStream_t stream) {
  const float* Q  = (const float*)d_in[0];
  const float* K  = (const float*)d_in[1];
  const float* V  = (const float*)d_in[2];
  const unsigned char* mask = (const unsigned char*)d_in[3];
  const float* Wq = (const float*)d_in[4];
  const float* bq = (const float*)d_in[5];
  const float* Wk = (const float*)d_in[6];
  const float* bk = (const float*)d_in[7];
  const float* Wv = (const float*)d_in[8];
  const float* bv = (const float*)d_in[9];
  const float* Wo = (const float*)d_in[10];
  const float* bo = (const float*)d_in[11];
  const float* gamma = (const float*)d_in[12];
  const float* beta  = (const float*)d_in[13];

  char* ws = (char*)d_ws;
  bf16* wt = (bf16*)(ws + 0);            // [4][768][768] bf16   4,718,592 B
  bf16* qb = (bf16*)(ws + 4718592);      // [72][1024][64]       9,437,184 B
  bf16* kb = (bf16*)(ws + 14155776);     // [72][1024][64]       9,437,184 B
  bf16* vt = (bf16*)(ws + 23592960);     // [72][64][1024]       9,437,184 B
  bf16* ctx = qb;                        // alias: qb dead after k_scores
  float* x  = (float*)(ws + 14155776);   // alias: kb+vt dead after k_ctx

  float* out  = (float*)d_out;                   // [6][1024][768]
  float* attn = out + (size_t)B*S*DM;            // [6][12][1024][1024]

  k_wt     <<<dim3(2304,4),  256, 0, stream>>>(Wq,Wk,Wv,Wo,wt);
  k_proj   <<<dim3(48,6,3),  256, 0, stream>>>(Q,K,V,wt,bq,bk,bv,qb,kb,vt);
  k_scores <<<dim3(8,8,BH),  256, 0, stream>>>(qb,kb,mask,attn);
  k_softmax<<<dim3(BH*S),    256, 0, stream>>>(attn);
  k_ctx    <<<dim3(4,1,BH),  256, 0, stream>>>(attn,vt,ctx);
  k_oproj  <<<dim3(48,6),    256, 0, stream>>>(ctx, wt + (size_t)3*DM*DM, bo, Q, x);
  k_ln     <<<dim3(M),       256, 0, stream>>>(x,gamma,beta,out);
}

// Round 3
// 436.328 us; speedup vs baseline: 2.1331x; 1.3603x over previous
//
#include <hip/hip_runtime.h>
#include <hip/hip_bf16.h>

#define B 6
#define S 1024
#define H 12
#define DK 64
#define DM 768
#define M (B*S)      // 6144
#define BH (B*H)     // 72

typedef __bf16 bf16;
typedef __attribute__((ext_vector_type(8))) __bf16 bf16x8;
typedef __attribute__((ext_vector_type(4))) float f32x4;

// ---------------- weight transpose + bf16 convert: wt[z][n][k] = W_z[k][n]
__global__ void k_wt(const float* __restrict__ Wq, const float* __restrict__ Wk,
                     const float* __restrict__ Wv, const float* __restrict__ Wo,
                     bf16* __restrict__ wt) {
  int z = blockIdx.y;
  const float* W = z==0?Wq : z==1?Wk : z==2?Wv : Wo;
  int idx = blockIdx.x*256 + threadIdx.x;   // 0..768*768-1
  int k = idx / DM, n = idx % DM;
  wt[(size_t)z*DM*DM + (size_t)n*DM + k] = (bf16)W[idx];
}

__device__ __forceinline__ bf16x8 cvt8(const float* p) {
  float4 u0 = *(const float4*)p;
  float4 u1 = *(const float4*)(p + 4);
  bf16x8 r;
  r[0]=(bf16)u0.x; r[1]=(bf16)u0.y; r[2]=(bf16)u0.z; r[3]=(bf16)u0.w;
  r[4]=(bf16)u1.x; r[5]=(bf16)u1.y; r[6]=(bf16)u1.z; r[7]=(bf16)u1.w;
  return r;
}

// ---------------- QKV projection: 128x128 tile, 4 waves 2x2, each wave 4x4 frags
__global__ void k_proj(const float* __restrict__ Q, const float* __restrict__ K,
                       const float* __restrict__ V,
                       const bf16* __restrict__ wt,
                       const float* __restrict__ bq, const float* __restrict__ bk,
                       const float* __restrict__ bv,
                       bf16* __restrict__ qb, bf16* __restrict__ kb, bf16* __restrict__ vt) {
  int z = blockIdx.z;
  const float* X    = z==0?Q : z==1?K : V;
  const float* bias = z==0?bq : z==1?bk : bv;
  const bf16* Wt = wt + (size_t)z*DM*DM;
  int tid = threadIdx.x, lane = tid & 63, w = tid >> 6;
  int wr = w >> 1, wc = w & 1;
  int lr = lane & 15, lg = lane >> 4;
  int m0 = blockIdx.x*128 + wr*64;
  int n0 = blockIdx.y*128 + wc*64;
  const float* abase = X  + (size_t)(m0+lr)*DM;
  const bf16*  bbase = Wt + (size_t)(n0+lr)*DM;
  f32x4 acc[4][4];
  #pragma unroll
  for (int i=0;i<4;++i)
    #pragma unroll
    for (int j=0;j<4;++j) acc[i][j] = (f32x4){0.f,0.f,0.f,0.f};
  for (int k0 = 0; k0 < DM; k0 += 32) {
    bf16x8 af[4], bfr[4];
    #pragma unroll
    for (int mi=0;mi<4;++mi) af[mi] = cvt8(abase + (size_t)mi*16*DM + k0 + lg*8);
    #pragma unroll
    for (int ni=0;ni<4;++ni) bfr[ni] = *(const bf16x8*)(bbase + (size_t)ni*16*DM + k0 + lg*8);
    #pragma unroll
    for (int mi=0;mi<4;++mi)
      #pragma unroll
      for (int ni=0;ni<4;++ni)
        acc[mi][ni] = __builtin_amdgcn_mfma_f32_16x16x32_bf16(af[mi], bfr[ni], acc[mi][ni], 0,0,0);
  }
  #pragma unroll
  for (int ni=0;ni<4;++ni) {
    int n = n0 + ni*16 + lr;
    float bs = bias[n];
    int h = n >> 6, d = n & 63;
    #pragma unroll
    for (int mi=0;mi<4;++mi)
      #pragma unroll
      for (int r=0;r<4;++r) {
        int m = m0 + mi*16 + lg*4 + r;
        int bb = m >> 10, s = m & 1023;
        float val = acc[mi][ni][r] + bs;
        if (z == 0)      qb[((size_t)(bb*H + h)*S + s)*DK + d] = (bf16)val;
        else if (z == 1) kb[((size_t)(bb*H + h)*S + s)*DK + d] = (bf16)val;
        else             vt[((size_t)(bb*H + h)*DK + d)*S + s] = (bf16)val;
      }
  }
}

// ---------------- fused scores + mask + softmax + attn-write + PV
// block: 256 threads, handles (bh, 16 q-rows). wave w owns k-cols [w*256, w*256+256).
__global__ __launch_bounds__(256) void k_fattn(
    const bf16* __restrict__ qb, const bf16* __restrict__ kb,
    const bf16* __restrict__ vt, const unsigned char* __restrict__ mask,
    float* __restrict__ attn, bf16* __restrict__ ctx) {
  int bh = blockIdx.y; int b = bh / H, h = bh - b*H;
  int q0 = blockIdx.x * 16;
  int tid = threadIdx.x, lane = tid & 63, w = tid >> 6;
  int lr = lane & 15, lg = lane >> 4;

  __shared__ bf16  p_lds[16][1032];        // padded: +8 bf16 per row
  __shared__ float redm[4][16];
  __shared__ float redl[4][16];
  __shared__ float ctxred[4][16][64];

  // ---- QK^T : wave computes S[16][256] chunk
  const bf16* qbase = qb + ((size_t)bh*S + q0 + lr)*DK + lg*8;
  bf16x8 qa0 = *(const bf16x8*)(qbase);
  bf16x8 qa1 = *(const bf16x8*)(qbase + 32);
  f32x4 sc[16];
  #pragma unroll
  for (int ni=0;ni<16;++ni) sc[ni] = (f32x4){0.f,0.f,0.f,0.f};
  const bf16* kbase = kb + ((size_t)bh*S + w*256 + lr)*DK + lg*8;
  #pragma unroll
  for (int ni=0;ni<16;++ni) {
    bf16x8 kf0 = *(const bf16x8*)(kbase + (size_t)ni*16*DK);
    bf16x8 kf1 = *(const bf16x8*)(kbase + (size_t)ni*16*DK + 32);
    sc[ni] = __builtin_amdgcn_mfma_f32_16x16x32_bf16(qa0, kf0, sc[ni], 0,0,0);
    sc[ni] = __builtin_amdgcn_mfma_f32_16x16x32_bf16(qa1, kf1, sc[ni], 0,0,0);
  }

  // ---- mask + scale (C layout: row=lg*4+r, col=ni*16+lr)
  const unsigned char* mbase = mask + ((size_t)b*S + q0)*S + w*256;
  #pragma unroll
  for (int ni=0;ni<16;++ni)
    #pragma unroll
    for (int r=0;r<4;++r) {
      int row = lg*4 + r;
      unsigned char mk = mbase[(size_t)row*S + ni*16 + lr];
      sc[ni][r] = mk ? -1e9f : sc[ni][r]*0.125f;
    }

  // ---- row max (per lane over ni, butterfly over lr bits, LDS over waves)
  float mrow[4];
  #pragma unroll
  for (int r=0;r<4;++r) {
    float m = sc[0][r];
    #pragma unroll
    for (int ni=1;ni<16;++ni) m = fmaxf(m, sc[ni][r]);
    m = fmaxf(m, __shfl_xor(m, 1));
    m = fmaxf(m, __shfl_xor(m, 2));
    m = fmaxf(m, __shfl_xor(m, 4));
    m = fmaxf(m, __shfl_xor(m, 8));
    mrow[r] = m;
  }
  if (lr == 0) {
    #pragma unroll
    for (int r=0;r<4;++r) redm[w][lg*4+r] = mrow[r];
  }
  __syncthreads();
  #pragma unroll
  for (int r=0;r<4;++r) {
    int row = lg*4 + r;
    mrow[r] = fmaxf(fmaxf(redm[0][row], redm[1][row]),
                    fmaxf(redm[2][row], redm[3][row]));
  }

  // ---- exp + row sum
  float lrow[4] = {0.f,0.f,0.f,0.f};
  #pragma unroll
  for (int ni=0;ni<16;++ni)
    #pragma unroll
    for (int r=0;r<4;++r) {
      float p = __expf(sc[ni][r] - mrow[r]);
      sc[ni][r] = p;
      lrow[r] += p;
    }
  #pragma unroll
  for (int r=0;r<4;++r) {
    float s = lrow[r];
    s += __shfl_xor(s, 1);
    s += __shfl_xor(s, 2);
    s += __shfl_xor(s, 4);
    s += __shfl_xor(s, 8);
    lrow[r] = s;
  }
  if (lr == 0) {
    #pragma unroll
    for (int r=0;r<4;++r) redl[w][lg*4+r] = lrow[r];
  }
  __syncthreads();
  float inv[4];
  #pragma unroll
  for (int r=0;r<4;++r) {
    int row = lg*4 + r;
    inv[r] = 1.f / (redl[0][row] + redl[1][row] + redl[2][row] + redl[3][row]);
  }

  // ---- write normalized attn (f32, once) + stage p into LDS (bf16)
  float* abase = attn + ((size_t)bh*S + q0)*S + w*256;
  #pragma unroll
  for (int ni=0;ni<16;++ni)
    #pragma unroll
    for (int r=0;r<4;++r) {
      int row = lg*4 + r;
      float pv = sc[ni][r] * inv[r];
      abase[(size_t)row*S + ni*16 + lr] = pv;
      p_lds[row][w*256 + ni*16 + lr] = (bf16)pv;
    }
  // p_lds written & read by the SAME wave -> no barrier needed (lgkmcnt only)

  // ---- PV over this wave's 256-col chunk: partial ctx[16][64]
  f32x4 cacc[4];
  #pragma unroll
  for (int d=0;d<4;++d) cacc[d] = (f32x4){0.f,0.f,0.f,0.f};
  const bf16* vbase = vt + (size_t)bh*DK*S + w*256 + lg*8;
  #pragma unroll
  for (int ks=0;ks<8;++ks) {
    bf16x8 pa = *(const bf16x8*)&p_lds[lr][w*256 + ks*32 + lg*8];
    #pragma unroll
    for (int d=0;d<4;++d) {
      bf16x8 vf = *(const bf16x8*)(vbase + (size_t)(d*16+lr)*S + ks*32);
      cacc[d] = __builtin_amdgcn_mfma_f32_16x16x32_bf16(pa, vf, cacc[d], 0,0,0);
    }
  }

  // ---- cross-wave reduce of ctx partials, then global write
  #pragma unroll
  for (int d=0;d<4;++d)
    #pragma unroll
    for (int r=0;r<4;++r)
      ctxred[w][lg*4+r][d*16+lr] = cacc[d][r];
  __syncthreads();
  int col = tid & 63, row4 = tid >> 6;
  #pragma unroll
  for (int i=0;i<4;++i) {
    int row = row4*4 + i;
    float s = ctxred[0][row][col] + ctxred[1][row][col]
            + ctxred[2][row][col] + ctxred[3][row][col];
    ctx[((size_t)b*S + q0 + row)*DM + h*DK + col] = (bf16)s;
  }
}

// ---------------- out projection + bias + residual -> x (f32)
__global__ void k_oproj(const bf16* __restrict__ ctx, const bf16* __restrict__ wto,
                        const float* __restrict__ bo, const float* __restrict__ res,
                        float* __restrict__ x) {
  int tid = threadIdx.x, lane = tid & 63, w = tid >> 6;
  int wr = w >> 1, wc = w & 1;
  int lr = lane & 15, lg = lane >> 4;
  int m0 = blockIdx.x*128 + wr*64;
  int n0 = blockIdx.y*128 + wc*64;
  const bf16* abase = ctx + (size_t)(m0+lr)*DM;
  const bf16* bbase = wto + (size_t)(n0+lr)*DM;
  f32x4 acc[4][4];
  #pragma unroll
  for (int i=0;i<4;++i)
    #pragma unroll
    for (int j=0;j<4;++j) acc[i][j] = (f32x4){0.f,0.f,0.f,0.f};
  for (int k0 = 0; k0 < DM; k0 += 32) {
    bf16x8 af[4], bfr[4];
    #pragma unroll
    for (int mi=0;mi<4;++mi) af[mi]  = *(const bf16x8*)(abase + (size_t)mi*16*DM + k0 + lg*8);
    #pragma unroll
    for (int ni=0;ni<4;++ni) bfr[ni] = *(const bf16x8*)(bbase + (size_t)ni*16*DM + k0 + lg*8);
    #pragma unroll
    for (int mi=0;mi<4;++mi)
      #pragma unroll
      for (int ni=0;ni<4;++ni)
        acc[mi][ni] = __builtin_amdgcn_mfma_f32_16x16x32_bf16(af[mi], bfr[ni], acc[mi][ni], 0,0,0);
  }
  #pragma unroll
  for (int ni=0;ni<4;++ni) {
    int n = n0 + ni*16 + lr;
    float bb = bo[n];
    #pragma unroll
    for (int mi=0;mi<4;++mi)
      #pragma unroll
      for (int r=0;r<4;++r) {
        int m = m0 + mi*16 + lg*4 + r;
        x[(size_t)m*DM + n] = acc[mi][ni][r] + bb + res[(size_t)m*DM + n];
      }
  }
}

// ---------------- layernorm rows of 768 -> d_out
__global__ void k_ln(const float* __restrict__ x, const float* __restrict__ gamma,
                     const float* __restrict__ beta, float* __restrict__ out) {
  int row = blockIdx.x; int tid = threadIdx.x;
  const float* xr = x + (size_t)row*DM;
  float v0 = xr[tid], v1 = xr[tid+256], v2 = xr[tid+512];
  float s = v0+v1+v2, ss = v0*v0+v1*v1+v2*v2;
  #pragma unroll
  for (int off=32; off; off>>=1){ s += __shfl_xor(s,off); ss += __shfl_xor(ss,off); }
  __shared__ float sm[8];
  int w = tid>>6;
  if ((tid&63)==0){ sm[w]=s; sm[4+w]=ss; }
  __syncthreads();
  s = sm[0]+sm[1]+sm[2]+sm[3]; ss = sm[4]+sm[5]+sm[6]+sm[7];
  float mean = s * (1.f/DM);
  float var = ss * (1.f/DM) - mean*mean;
  float rstd = rsqrtf(var + 1e-5f);
  out[(size_t)row*DM + tid]     = (v0-mean)*rstd*gamma[tid]     + beta[tid];
  out[(size_t)row*DM + tid+256] = (v1-mean)*rstd*gamma[tid+256] + beta[tid+256];
  out[(size_t)row*DM + tid+512] = (v2-mean)*rstd*gamma[tid+512] + beta[tid+512];
}

extern "C" void kernel_launch(void* const* d_in, const int* in_sizes, int n_in,
                              void* d_out, int out_size, void* d_ws, size_t ws_size,
                              hipStream_t stream) {
  const float* Q  = (const float*)d_in[0];
  const float* K  = (const float*)d_in[1];
  const float* V  = (const float*)d_in[2];
  const unsigned char* mask = (const unsigned char*)d_in[3];
  const float* Wq = (const float*)d_in[4];
  const float* bq = (const float*)d_in[5];
  const float* Wk = (const float*)d_in[6];
  const float* bk = (const float*)d_in[7];
  const float* Wv = (const float*)d_in[8];
  const float* bv = (const float*)d_in[9];
  const float* Wo = (const float*)d_in[10];
  const float* bo = (const float*)d_in[11];
  const float* gamma = (const float*)d_in[12];
  const float* beta  = (const float*)d_in[13];

  char* ws = (char*)d_ws;
  bf16* wt  = (bf16*)(ws + 0);            // [4][768][768] bf16   4,718,592 B
  bf16* qb  = (bf16*)(ws + 4718592);      // [72][1024][64]       9,437,184 B
  bf16* kb  = (bf16*)(ws + 14155776);     // [72][1024][64]       9,437,184 B
  bf16* vt  = (bf16*)(ws + 23592960);     // [72][64][1024]       9,437,184 B
  bf16* ctx = (bf16*)(ws + 33030144);     // [6][1024][768]       9,437,184 B
  float* x  = (float*)(ws + 14155776);    // alias kb+vt (dead after k_fattn)

  float* out  = (float*)d_out;                   // [6][1024][768]
  float* attn = out + (size_t)B*S*DM;            // [6][12][1024][1024]

  k_wt    <<<dim3(2304,4),  256, 0, stream>>>(Wq,Wk,Wv,Wo,wt);
  k_proj  <<<dim3(48,6,3),  256, 0, stream>>>(Q,K,V,wt,bq,bk,bv,qb,kb,vt);
  k_fattn <<<dim3(64,BH),   256, 0, stream>>>(qb,kb,vt,mask,attn,ctx);
  k_oproj <<<dim3(48,6),    256, 0, stream>>>(ctx, wt + (size_t)3*DM*DM, bo, Q, x);
  k_ln    <<<dim3(M),       256, 0, stream>>>(x,gamma,beta,out);
}